// Round 1
// baseline (250.322 us; speedup 1.0000x reference)
//
#include <hip/hip_runtime.h>
#include <stdint.h>

// ---------------------------------------------------------------------------
// CausalSelfAttention (T=4096, DIM=1024, 16 heads x 64) on gfx950, bf16 MFMA.
// Pipeline: cast->bf16 | rope tables | GEMM1 qkv | fuse(vmix,rms,rope) |
//           transpose V | flash attention | GEMM2 -> fp32 out
// ---------------------------------------------------------------------------

typedef __attribute__((ext_vector_type(8))) __bf16 bf16x8;
typedef __attribute__((ext_vector_type(8))) unsigned short u16x8;
typedef __attribute__((ext_vector_type(4))) float f32x4;

union U8 { u16x8 s; bf16x8 b; };

__device__ __forceinline__ float bf2f(unsigned short u) {
  union { unsigned int i; float f; } c; c.i = ((unsigned int)u) << 16; return c.f;
}
__device__ __forceinline__ unsigned short f2bf(float f) {
  union { float f; unsigned int i; } c; c.f = f;
  return (unsigned short)((c.i + 0x7fffu + ((c.i >> 16) & 1u)) >> 16);
}

// async global->LDS, 16B per lane; LDS dest is wave-uniform base + lane*16
#define GLOAD16(gp, lp)                                                         \
  __builtin_amdgcn_global_load_lds(                                             \
      (const __attribute__((address_space(1))) void*)(gp),                      \
      (__attribute__((address_space(3))) void*)(lp), 16, 0, 0)

#define MFMA16(a, b, c) __builtin_amdgcn_mfma_f32_16x16x32_bf16((a), (b), (c), 0, 0, 0)

constexpr float ATTN_SCALE = 0.12f;
constexpr float LOG2E = 1.44269504088896340736f;

// --------------------------- rope tables -----------------------------------
__global__ void rope_tab(float* __restrict__ ct, float* __restrict__ st) {
  const int i = blockIdx.x * 256 + threadIdx.x;
  if (i >= 4096 * 32) return;
  const int tt = i >> 5, k = i & 31;
  float cv = 1.0f, sv = 0.0f;
  if (k < 16) {
    const float af = powf(1.0f / 1024.0f, (float)k * (1.0f / 15.0f));
    const float th = (float)tt * af;
    cv = cosf(th);
    sv = sinf(th);
  }
  ct[i] = cv; st[i] = sv;
}

// --------------------------- f32 -> bf16 cast ------------------------------
__global__ void cast_f2b8(const float* __restrict__ in, unsigned short* __restrict__ out, int n8) {
  const int i = blockIdx.x * 256 + threadIdx.x;
  if (i >= n8) return;
  const float4 a = ((const float4*)in)[2 * i];
  const float4 b = ((const float4*)in)[2 * i + 1];
  u16x8 o;
  o[0] = f2bf(a.x); o[1] = f2bf(a.y); o[2] = f2bf(a.z); o[3] = f2bf(a.w);
  o[4] = f2bf(b.x); o[5] = f2bf(b.y); o[6] = f2bf(b.z); o[7] = f2bf(b.w);
  ((u16x8*)out)[i] = o;
}

// --------------------------- GEMM: C[M][N] = A[M][K] * B[N][K]^T -----------
// m97 structure: 128x128 tile, BK=32, 256 threads (4 waves), 4x4 16x16x32 frags
template <int OUT_BF16>
__global__ __launch_bounds__(256) void gemm_bt(
    const unsigned short* __restrict__ A, const unsigned short* __restrict__ B,
    void* __restrict__ Cout, int M, int N, int K) {
  __shared__ unsigned short lA[128 * 32];
  __shared__ unsigned short lB[128 * 32];
  const int nbn = N >> 7;
  const int bm = blockIdx.x / nbn, bn = blockIdx.x % nbn;
  const int t = threadIdx.x;
  const int w = t >> 6, l = t & 63;
  const int g = l >> 4, c = l & 15;
  const int wr = (w >> 1) * 64, wc = (w & 1) * 64;

  // staging: chunk i (16B): row = i>>2 (64B rows of [128][32] tile), col swizzled
  const int srow = t >> 2;
  const int scol = ((t & 3) << 4) ^ ((srow & 3) << 4);  // byte col, XOR swizzle
  const char* ga = (const char*)(A + (size_t)(bm * 128 + srow) * K) + scol;
  const char* gb = (const char*)(B + (size_t)(bn * 128 + srow) * K) + scol;
  const size_t rowK2 = (size_t)64 * K * 2;
  char* la_dst = (char*)lA + t * 16;
  char* lb_dst = (char*)lB + t * 16;

  f32x4 acc[4][4] = {};

  for (int kt = 0; kt < K; kt += 32) {
    const char* gak = ga + (size_t)kt * 2;
    const char* gbk = gb + (size_t)kt * 2;
    GLOAD16(gak, la_dst);
    GLOAD16(gak + rowK2, la_dst + 4096);
    GLOAD16(gbk, lb_dst);
    GLOAD16(gbk + rowK2, lb_dst + 4096);
    __syncthreads();
    U8 af[4], bfr[4];
#pragma unroll
    for (int mi = 0; mi < 4; ++mi) {
      const int row = wr + 16 * mi + c;
      af[mi].s = *(const u16x8*)((const char*)lA + row * 64 + ((16 * g) ^ ((row & 3) << 4)));
    }
#pragma unroll
    for (int ni = 0; ni < 4; ++ni) {
      const int row = wc + 16 * ni + c;
      bfr[ni].s = *(const u16x8*)((const char*)lB + row * 64 + ((16 * g) ^ ((row & 3) << 4)));
    }
#pragma unroll
    for (int mi = 0; mi < 4; ++mi)
#pragma unroll
      for (int ni = 0; ni < 4; ++ni)
        acc[mi][ni] = MFMA16(af[mi].b, bfr[ni].b, acc[mi][ni]);
    __syncthreads();
  }
#pragma unroll
  for (int mi = 0; mi < 4; ++mi) {
#pragma unroll
    for (int ni = 0; ni < 4; ++ni) {
#pragma unroll
      for (int r = 0; r < 4; ++r) {
        const int row = bm * 128 + wr + 16 * mi + 4 * g + r;
        const int col = bn * 128 + wc + 16 * ni + c;
        const float v = acc[mi][ni][r];
        if (OUT_BF16)
          ((unsigned short*)Cout)[(size_t)row * N + col] = f2bf(v);
        else
          ((float*)Cout)[(size_t)row * N + col] = v;
      }
    }
  }
}

// --------------------------- fuse: vmix + rmsnorm + rope -------------------
__device__ __forceinline__ void load64f(const unsigned short* p, float* x) {
#pragma unroll
  for (int j = 0; j < 8; ++j) {
    const u16x8 v = *(const u16x8*)(p + 8 * j);
#pragma unroll
    for (int e = 0; e < 8; ++e) x[8 * j + e] = bf2f(v[e]);
  }
}

__device__ __forceinline__ void rmsrope_store(const float* x, const float* ct, const float* st,
                                              unsigned short* outp) {
  float ms = 0.f;
#pragma unroll
  for (int j = 0; j < 64; ++j) ms += x[j] * x[j];
  const float sc = rsqrtf(ms * (1.0f / 64.0f) + 1.1920928955078125e-7f);
  float y[64];
#pragma unroll
  for (int j = 0; j < 32; ++j) {
    const float cc = ct[j], ss = st[j];
    const float a = x[j] * sc, b = x[j + 32] * sc;
    y[j] = a * cc + b * ss;
    y[j + 32] = b * cc - a * ss;
  }
#pragma unroll
  for (int j = 0; j < 8; ++j) {
    u16x8 o;
#pragma unroll
    for (int e = 0; e < 8; ++e) o[e] = f2bf(y[8 * j + e]);
    *(u16x8*)(outp + 8 * j) = o;
  }
}

__global__ __launch_bounds__(256) void fuse_qkv(
    const unsigned short* __restrict__ qkv,  // [4096][3072] bf16
    const float* __restrict__ ve,            // [4096][1024]
    const float* __restrict__ lam,           // [2]
    const float* __restrict__ ct, const float* __restrict__ st,  // [4096][32]
    unsigned short* __restrict__ Qo,  // [16][4096][64]
    unsigned short* __restrict__ Ko,  // [16][4096][64]
    unsigned short* __restrict__ Vo)  // [16][4096][64]
{
  const int gid = blockIdx.x * 256 + threadIdx.x;  // 65536 = 4096 t * 16 h
  const int tt = gid >> 4, h = gid & 15;
  const unsigned short* base = qkv + (size_t)tt * 3072 + h * 64;
  const float* ctp = ct + tt * 32;
  const float* stp = st + tt * 32;
  float x[64];
  load64f(base, x);
  rmsrope_store(x, ctp, stp, Qo + ((size_t)h * 4096 + tt) * 64);
  load64f(base + 1024, x);
  rmsrope_store(x, ctp, stp, Ko + ((size_t)h * 4096 + tt) * 64);
  // v mix
  const float l0 = lam[0], l1 = lam[1];
  const float* vp = ve + (size_t)tt * 1024 + h * 64;
  load64f(base + 2048, x);
  unsigned short* vo = Vo + ((size_t)h * 4096 + tt) * 64;
#pragma unroll
  for (int j = 0; j < 8; ++j) {
    u16x8 o;
#pragma unroll
    for (int e = 0; e < 8; ++e) o[e] = f2bf(l0 * x[8 * j + e] + l1 * vp[8 * j + e]);
    *(u16x8*)(vo + 8 * j) = o;
  }
}

// --------------------------- V transpose: [16][4096][64] -> [16][64][4096] -
__global__ __launch_bounds__(256) void transpose_v(const unsigned short* __restrict__ vin,
                                                   unsigned short* __restrict__ vout) {
  __shared__ unsigned short tile[64][72];
  const int h = (int)(blockIdx.x & 15), tb = (int)(blockIdx.x >> 4);
  const int t = threadIdx.x;
  const int r = t >> 2, c0 = (t & 3) * 16;
  const unsigned short* src = vin + ((size_t)h * 4096 + tb * 64 + r) * 64 + c0;
#pragma unroll
  for (int j = 0; j < 16; ++j) tile[c0 + j][r] = src[j];
  __syncthreads();
  unsigned short* dst = vout + ((size_t)h * 64 + r) * 4096 + tb * 64 + c0;
#pragma unroll
  for (int j = 0; j < 16; ++j) dst[j] = tile[r][c0 + j];
}

// --------------------------- flash attention -------------------------------
// block = (head, 64-row q block), 4 waves x 16 q rows. KV tiles of 64.
// K tile LDS [64][64] bf16 (128B rows), XOR swizzle byte^((row&7)<<4) applied
// on the GLOBAL source so global_load_lds stays linear; reads un-swizzle.
__global__ __launch_bounds__(256) void attn_fa(
    const unsigned short* __restrict__ Q,   // [16][4096][64]
    const unsigned short* __restrict__ Kv,  // [16][4096][64]
    const unsigned short* __restrict__ VT,  // [16][64][4096]
    unsigned short* __restrict__ Y)         // [4096][1024]
{
  __shared__ unsigned short lk[64 * 64];
  __shared__ unsigned short lvt[64 * 64];
  __shared__ unsigned short lp[4][16 * 72];  // per-wave P tile, +16B row pad

  const int h = (int)(blockIdx.x & 15);
  const int qb = 63 - (int)(blockIdx.x >> 4);  // descending: longest first
  const int t = threadIdx.x;
  const int w = t >> 6, l = t & 63;
  const int g = l >> 4, c = l & 15;
  const int q0 = qb * 64;

  // Q fragments (A operand: row = q (l&15), k = d contiguous 8 per lane-group)
  U8 qf0, qf1;
  {
    const unsigned short* qp = Q + ((size_t)h * 4096 + (q0 + 16 * w + c)) * 64 + 8 * g;
    qf0.s = *(const u16x8*)qp;
    qf1.s = *(const u16x8*)(qp + 32);
  }

  f32x4 acc_o[4] = {};
  float m[4], ls[4];
#pragma unroll
  for (int r = 0; r < 4; ++r) { m[r] = -1e30f; ls[r] = 0.0f; }

  const int srow = t >> 3;                               // 0..31
  const int csw = ((t & 7) << 4) ^ ((srow & 7) << 4);    // swizzled byte col
  const unsigned short* kbase = Kv + (size_t)h * 4096 * 64;
  const unsigned short* vbase = VT + (size_t)h * 64 * 4096;
  char* lk0 = (char*)lk + t * 16;
  char* lv0 = (char*)lvt + t * 16;

  for (int kvi = 0; kvi <= qb; ++kvi) {
    const int kv0 = kvi * 64;
    GLOAD16((const char*)(kbase + (size_t)(kv0 + srow) * 64) + csw, lk0);
    GLOAD16((const char*)(kbase + (size_t)(kv0 + srow + 32) * 64) + csw, lk0 + 4096);
    GLOAD16((const char*)(vbase + (size_t)srow * 4096 + kv0) + csw, lv0);
    GLOAD16((const char*)(vbase + (size_t)(srow + 32) * 4096 + kv0) + csw, lv0 + 4096);
    __syncthreads();

    // S = Q K^T  (per wave: 16 q x 64 kv)
    f32x4 s[4];
#pragma unroll
    for (int f = 0; f < 4; ++f) {
      const int row = 16 * f + c;
      const int sw = (row & 7) << 4;
      U8 k0, k1;
      k0.s = *(const u16x8*)((const char*)lk + row * 128 + ((16 * g) ^ sw));
      k1.s = *(const u16x8*)((const char*)lk + row * 128 + ((16 * g + 64) ^ sw));
      f32x4 z = {0.f, 0.f, 0.f, 0.f};
      z = MFMA16(qf0.b, k0.b, z);
      z = MFMA16(qf1.b, k1.b, z);
      s[f] = z;
    }
    // causal mask (only the diagonal tile needs it)
    if (kvi == qb) {
#pragma unroll
      for (int f = 0; f < 4; ++f) {
        const int kvcol = kv0 + 16 * f + c;
#pragma unroll
        for (int r = 0; r < 4; ++r) {
          const int qq = q0 + 16 * w + 4 * g + r;
          if (kvcol > qq) s[f][r] = -1e30f;
        }
      }
    }
    // online softmax: rows live in (group g, reg r), cols across 16 lanes
    float alpha[4];
#pragma unroll
    for (int r = 0; r < 4; ++r) {
      float rm = fmaxf(fmaxf(s[0][r], s[1][r]), fmaxf(s[2][r], s[3][r]));
      rm = fmaxf(rm, __shfl_xor(rm, 1));
      rm = fmaxf(rm, __shfl_xor(rm, 2));
      rm = fmaxf(rm, __shfl_xor(rm, 4));
      rm = fmaxf(rm, __shfl_xor(rm, 8));
      const float mn = fmaxf(m[r], rm * ATTN_SCALE);
      float rs = 0.f;
#pragma unroll
      for (int f = 0; f < 4; ++f) {
        const float p = exp2f((s[f][r] * ATTN_SCALE - mn) * LOG2E);
        s[f][r] = p;
        rs += p;
      }
      rs += __shfl_xor(rs, 1);
      rs += __shfl_xor(rs, 2);
      rs += __shfl_xor(rs, 4);
      rs += __shfl_xor(rs, 8);
      const float a = exp2f((m[r] - mn) * LOG2E);
      alpha[r] = a;
      ls[r] = ls[r] * a + rs;
      m[r] = mn;
    }
#pragma unroll
    for (int df = 0; df < 4; ++df)
#pragma unroll
      for (int r = 0; r < 4; ++r) acc_o[df][r] *= alpha[r];

    // P -> per-wave LDS (re-layout for PV A-operand)
    unsigned short* lpw = &lp[w][0];
#pragma unroll
    for (int f = 0; f < 4; ++f)
#pragma unroll
      for (int r = 0; r < 4; ++r)
        lpw[(4 * g + r) * 72 + 16 * f + c] = f2bf(s[f][r]);

    // O += P V   (A = P [16q x 64kv], B = V^T rows d, k = kv contiguous)
#pragma unroll
    for (int half = 0; half < 2; ++half) {
      U8 pf;
      pf.s = *(const u16x8*)((const char*)lpw + c * 144 + 16 * g + 64 * half);
#pragma unroll
      for (int df = 0; df < 4; ++df) {
        const int row = 16 * df + c;
        const int sw = (row & 7) << 4;
        U8 vf;
        vf.s = *(const u16x8*)((const char*)lvt + row * 128 + ((16 * g + 64 * half) ^ sw));
        acc_o[df] = MFMA16(pf.b, vf.b, acc_o[df]);
      }
    }
    __syncthreads();
  }

  // epilogue: y = O / l, write [t][h*64+d]
#pragma unroll
  for (int r = 0; r < 4; ++r) {
    const float inv = 1.0f / ls[r];
    const int qq = q0 + 16 * w + 4 * g + r;
#pragma unroll
    for (int df = 0; df < 4; ++df)
      Y[(size_t)qq * 1024 + h * 64 + 16 * df + c] = f2bf(acc_o[df][r] * inv);
  }
}

// --------------------------- launcher --------------------------------------
extern "C" void kernel_launch(void* const* d_in, const int* in_sizes, int n_in,
                              void* d_out, int out_size, void* d_ws, size_t ws_size,
                              hipStream_t stream) {
  const float* x   = (const float*)d_in[0];
  const float* ve  = (const float*)d_in[1];
  const float* qw  = (const float*)d_in[2];
  const float* lam = (const float*)d_in[3];
  const float* pw  = (const float*)d_in[4];
  float* out = (float*)d_out;

  unsigned short* ws = (unsigned short*)d_ws;
  unsigned short* x_bf  = ws;                                // 4096*1024
  unsigned short* wqkv  = x_bf + (size_t)4096 * 1024;        // 3072*1024
  unsigned short* wproj = wqkv + (size_t)3072 * 1024;        // 1024*1024
  unsigned short* qkv   = wproj + (size_t)1024 * 1024;       // 4096*3072
  unsigned short* Qr    = qkv + (size_t)4096 * 3072;         // 16*4096*64
  unsigned short* Kr    = Qr + (size_t)4096 * 1024;
  unsigned short* Vm    = Kr + (size_t)4096 * 1024;
  unsigned short* VTt   = Vm + (size_t)4096 * 1024;
  unsigned short* Yb    = VTt + (size_t)4096 * 1024;
  float* ct = (float*)(Yb + (size_t)4096 * 1024);            // 4096*32
  float* st = ct + 4096 * 32;

  rope_tab<<<512, 256, 0, stream>>>(ct, st);
  cast_f2b8<<<2048, 256, 0, stream>>>(x, x_bf, 524288);
  cast_f2b8<<<1536, 256, 0, stream>>>(qw, wqkv, 393216);
  cast_f2b8<<<512, 256, 0, stream>>>(pw, wproj, 131072);
  gemm_bt<1><<<768, 256, 0, stream>>>(x_bf, wqkv, (void*)qkv, 4096, 3072, 1024);
  fuse_qkv<<<256, 256, 0, stream>>>(qkv, ve, lam, ct, st, Qr, Kr, Vm);
  transpose_v<<<1024, 256, 0, stream>>>(Vm, VTt);
  attn_fa<<<1024, 256, 0, stream>>>(Qr, Kr, VTt, Yb);
  gemm_bt<0><<<256, 256, 0, stream>>>(Yb, wproj, (void*)out, 4096, 1024, 1024);
}

// Round 2
// 244.220 us; speedup vs baseline: 1.0250x; 1.0250x over previous
//
#include <hip/hip_runtime.h>
#include <stdint.h>

// ---------------------------------------------------------------------------
// CausalSelfAttention (T=4096, DIM=1024, 16 heads x 64) on gfx950, bf16 MFMA.
// Pipeline: cast->bf16 | rope tables | GEMM1 qkv | fuse(vmix,rms,rope) |
//           transpose V | flash attention (2-phase dbuf) | GEMM2 -> fp32 out
// ---------------------------------------------------------------------------

typedef __attribute__((ext_vector_type(8))) __bf16 bf16x8;
typedef __attribute__((ext_vector_type(8))) unsigned short u16x8;
typedef __attribute__((ext_vector_type(4))) float f32x4;

union U8 { u16x8 s; bf16x8 b; };

__device__ __forceinline__ float bf2f(unsigned short u) {
  union { unsigned int i; float f; } c; c.i = ((unsigned int)u) << 16; return c.f;
}
// native RNE convert (v_cvt_*_bf16) instead of 4-op manual emulation
__device__ __forceinline__ unsigned short f2bf(float f) {
  union { __bf16 h; unsigned short u; } c; c.h = (__bf16)f; return c.u;
}

// async global->LDS, 16B per lane; LDS dest is wave-uniform base + lane*16
#define GLOAD16(gp, lp)                                                         \
  __builtin_amdgcn_global_load_lds(                                             \
      (const __attribute__((address_space(1))) void*)(gp),                      \
      (__attribute__((address_space(3))) void*)(lp), 16, 0, 0)

#define MFMA16(a, b, c) __builtin_amdgcn_mfma_f32_16x16x32_bf16((a), (b), (c), 0, 0, 0)

constexpr float ATTN_SCALE = 0.12f;
constexpr float LOG2E = 1.44269504088896340736f;
constexpr float QSCALE = ATTN_SCALE * LOG2E;  // folded into Q at fuse stage

// --------------------------- rope tables -----------------------------------
__global__ void rope_tab(float* __restrict__ ct, float* __restrict__ st) {
  const int i = blockIdx.x * 256 + threadIdx.x;
  if (i >= 4096 * 32) return;
  const int tt = i >> 5, k = i & 31;
  float cv = 1.0f, sv = 0.0f;
  if (k < 16) {
    const float af = powf(1.0f / 1024.0f, (float)k * (1.0f / 15.0f));
    const float th = (float)tt * af;
    cv = cosf(th);
    sv = sinf(th);
  }
  ct[i] = cv; st[i] = sv;
}

// --------------------------- f32 -> bf16 cast ------------------------------
__global__ void cast_f2b8(const float* __restrict__ in, unsigned short* __restrict__ out, int n8) {
  const int i = blockIdx.x * 256 + threadIdx.x;
  if (i >= n8) return;
  const float4 a = ((const float4*)in)[2 * i];
  const float4 b = ((const float4*)in)[2 * i + 1];
  u16x8 o;
  o[0] = f2bf(a.x); o[1] = f2bf(a.y); o[2] = f2bf(a.z); o[3] = f2bf(a.w);
  o[4] = f2bf(b.x); o[5] = f2bf(b.y); o[6] = f2bf(b.z); o[7] = f2bf(b.w);
  ((u16x8*)out)[i] = o;
}

// --------------------------- GEMM: C[M][N] = A[M][K] * B[N][K]^T -----------
// m97 structure: 128x128 tile, BK=32, 256 threads (4 waves), 4x4 16x16x32 frags
template <int OUT_BF16>
__global__ __launch_bounds__(256) void gemm_bt(
    const unsigned short* __restrict__ A, const unsigned short* __restrict__ B,
    void* __restrict__ Cout, int M, int N, int K) {
  __shared__ unsigned short lA[128 * 32];
  __shared__ unsigned short lB[128 * 32];
  const int nbn = N >> 7;
  const int bm = blockIdx.x / nbn, bn = blockIdx.x % nbn;
  const int t = threadIdx.x;
  const int w = t >> 6, l = t & 63;
  const int g = l >> 4, c = l & 15;
  const int wr = (w >> 1) * 64, wc = (w & 1) * 64;

  // staging: chunk i (16B): row = i>>2 (64B rows of [128][32] tile), col swizzled
  const int srow = t >> 2;
  const int scol = ((t & 3) << 4) ^ ((srow & 3) << 4);  // byte col, XOR swizzle
  const char* ga = (const char*)(A + (size_t)(bm * 128 + srow) * K) + scol;
  const char* gb = (const char*)(B + (size_t)(bn * 128 + srow) * K) + scol;
  const size_t rowK2 = (size_t)64 * K * 2;
  char* la_dst = (char*)lA + t * 16;
  char* lb_dst = (char*)lB + t * 16;

  f32x4 acc[4][4] = {};

  for (int kt = 0; kt < K; kt += 32) {
    const char* gak = ga + (size_t)kt * 2;
    const char* gbk = gb + (size_t)kt * 2;
    GLOAD16(gak, la_dst);
    GLOAD16(gak + rowK2, la_dst + 4096);
    GLOAD16(gbk, lb_dst);
    GLOAD16(gbk + rowK2, lb_dst + 4096);
    __syncthreads();
    U8 af[4], bfr[4];
#pragma unroll
    for (int mi = 0; mi < 4; ++mi) {
      const int row = wr + 16 * mi + c;
      af[mi].s = *(const u16x8*)((const char*)lA + row * 64 + ((16 * g) ^ ((row & 3) << 4)));
    }
#pragma unroll
    for (int ni = 0; ni < 4; ++ni) {
      const int row = wc + 16 * ni + c;
      bfr[ni].s = *(const u16x8*)((const char*)lB + row * 64 + ((16 * g) ^ ((row & 3) << 4)));
    }
#pragma unroll
    for (int mi = 0; mi < 4; ++mi)
#pragma unroll
      for (int ni = 0; ni < 4; ++ni)
        acc[mi][ni] = MFMA16(af[mi].b, bfr[ni].b, acc[mi][ni]);
    __syncthreads();
  }
#pragma unroll
  for (int mi = 0; mi < 4; ++mi) {
#pragma unroll
    for (int ni = 0; ni < 4; ++ni) {
#pragma unroll
      for (int r = 0; r < 4; ++r) {
        const int row = bm * 128 + wr + 16 * mi + 4 * g + r;
        const int col = bn * 128 + wc + 16 * ni + c;
        const float v = acc[mi][ni][r];
        if (OUT_BF16)
          ((unsigned short*)Cout)[(size_t)row * N + col] = f2bf(v);
        else
          ((float*)Cout)[(size_t)row * N + col] = v;
      }
    }
  }
}

// --------------------------- fuse: vmix + rmsnorm + rope -------------------
__device__ __forceinline__ void load64f(const unsigned short* p, float* x) {
#pragma unroll
  for (int j = 0; j < 8; ++j) {
    const u16x8 v = *(const u16x8*)(p + 8 * j);
#pragma unroll
    for (int e = 0; e < 8; ++e) x[8 * j + e] = bf2f(v[e]);
  }
}

__device__ __forceinline__ void rmsrope_store(const float* x, const float* ct, const float* st,
                                              unsigned short* outp, float pscale) {
  float ms = 0.f;
#pragma unroll
  for (int j = 0; j < 64; ++j) ms += x[j] * x[j];
  const float sc = rsqrtf(ms * (1.0f / 64.0f) + 1.1920928955078125e-7f) * pscale;
  float y[64];
#pragma unroll
  for (int j = 0; j < 32; ++j) {
    const float cc = ct[j], ss = st[j];
    const float a = x[j] * sc, b = x[j + 32] * sc;
    y[j] = a * cc + b * ss;
    y[j + 32] = b * cc - a * ss;
  }
#pragma unroll
  for (int j = 0; j < 8; ++j) {
    u16x8 o;
#pragma unroll
    for (int e = 0; e < 8; ++e) o[e] = f2bf(y[8 * j + e]);
    *(u16x8*)(outp + 8 * j) = o;
  }
}

__global__ __launch_bounds__(256) void fuse_qkv(
    const unsigned short* __restrict__ qkv,  // [4096][3072] bf16
    const float* __restrict__ ve,            // [4096][1024]
    const float* __restrict__ lam,           // [2]
    const float* __restrict__ ct, const float* __restrict__ st,  // [4096][32]
    unsigned short* __restrict__ Qo,  // [16][4096][64]  (pre-scaled by QSCALE)
    unsigned short* __restrict__ Ko,  // [16][4096][64]
    unsigned short* __restrict__ Vo)  // [16][4096][64]
{
  const int gid = blockIdx.x * 256 + threadIdx.x;  // 65536 = 4096 t * 16 h
  const int tt = gid >> 4, h = gid & 15;
  const unsigned short* base = qkv + (size_t)tt * 3072 + h * 64;
  const float* ctp = ct + tt * 32;
  const float* stp = st + tt * 32;
  float x[64];
  load64f(base, x);
  rmsrope_store(x, ctp, stp, Qo + ((size_t)h * 4096 + tt) * 64, QSCALE);
  load64f(base + 1024, x);
  rmsrope_store(x, ctp, stp, Ko + ((size_t)h * 4096 + tt) * 64, 1.0f);
  // v mix
  const float l0 = lam[0], l1 = lam[1];
  const float* vp = ve + (size_t)tt * 1024 + h * 64;
  load64f(base + 2048, x);
  unsigned short* vo = Vo + ((size_t)h * 4096 + tt) * 64;
#pragma unroll
  for (int j = 0; j < 8; ++j) {
    u16x8 o;
#pragma unroll
    for (int e = 0; e < 8; ++e) o[e] = f2bf(l0 * x[8 * j + e] + l1 * vp[8 * j + e]);
    *(u16x8*)(vo + 8 * j) = o;
  }
}

// --------------------------- V transpose: [16][4096][64] -> [16][64][4096] -
__global__ __launch_bounds__(256) void transpose_v(const unsigned short* __restrict__ vin,
                                                   unsigned short* __restrict__ vout) {
  __shared__ unsigned short tile[64][72];
  const int h = (int)(blockIdx.x & 15), tb = (int)(blockIdx.x >> 4);
  const int t = threadIdx.x;
  const int r = t >> 2, c0 = (t & 3) * 16;
  const unsigned short* src = vin + ((size_t)h * 4096 + tb * 64 + r) * 64 + c0;
#pragma unroll
  for (int j = 0; j < 16; ++j) tile[c0 + j][r] = src[j];
  __syncthreads();
  unsigned short* dst = vout + ((size_t)h * 64 + r) * 4096 + tb * 64 + c0;
#pragma unroll
  for (int j = 0; j < 16; ++j) dst[j] = tile[r][c0 + j];
}

// --------------------------- flash attention -------------------------------
// block = (head, 64-row q block), 4 waves x 16 q rows. KV tiles of 64.
// 2-phase double-buffered staging: issue next tile's global_load_lds BEFORE
// computing the current tile; the single __syncthreads (vmcnt(0) drain) per
// iteration lands after compute has covered the load latency.
// Q is pre-scaled by ATTN_SCALE*log2(e) -> softmax works in exp2 domain.
__global__ __launch_bounds__(256) void attn_fa(
    const unsigned short* __restrict__ Q,   // [16][4096][64] (scaled)
    const unsigned short* __restrict__ Kv,  // [16][4096][64]
    const unsigned short* __restrict__ VT,  // [16][64][4096]
    unsigned short* __restrict__ Y)         // [4096][1024]
{
  __shared__ unsigned short lk[2][64 * 64];
  __shared__ unsigned short lvt[2][64 * 64];
  __shared__ unsigned short lp[4][16 * 72];  // per-wave P tile, padded rows

  const int h = (int)(blockIdx.x & 15);
  const int qb = 63 - (int)(blockIdx.x >> 4);  // descending: longest first
  const int t = threadIdx.x;
  const int w = t >> 6, l = t & 63;
  const int g = l >> 4, c = l & 15;
  const int q0 = qb * 64;

  // Q fragments (A operand: row = q (l&15), k = d contiguous 8 per lane-group)
  U8 qf0, qf1;
  {
    const unsigned short* qp = Q + ((size_t)h * 4096 + (q0 + 16 * w + c)) * 64 + 8 * g;
    qf0.s = *(const u16x8*)qp;
    qf1.s = *(const u16x8*)(qp + 32);
  }

  f32x4 acc_o[4] = {};
  float m[4], ls[4];
#pragma unroll
  for (int r = 0; r < 4; ++r) { m[r] = -1e30f; ls[r] = 0.0f; }

  const int srow = t >> 3;                               // 0..31
  const int csw = ((t & 7) << 4) ^ ((srow & 7) << 4);    // swizzled byte col
  const unsigned short* kbase = Kv + (size_t)h * 4096 * 64;
  const unsigned short* vbase = VT + (size_t)h * 64 * 4096;

#define STAGE(buf, kv0)                                                          \
  do {                                                                           \
    char* lkd = (char*)lk[buf] + t * 16;                                         \
    char* lvd = (char*)lvt[buf] + t * 16;                                        \
    GLOAD16((const char*)(kbase + (size_t)((kv0) + srow) * 64) + csw, lkd);      \
    GLOAD16((const char*)(kbase + (size_t)((kv0) + srow + 32) * 64) + csw,       \
            lkd + 4096);                                                         \
    GLOAD16((const char*)(vbase + (size_t)srow * 4096 + (kv0)) + csw, lvd);      \
    GLOAD16((const char*)(vbase + (size_t)(srow + 32) * 4096 + (kv0)) + csw,     \
            lvd + 4096);                                                         \
  } while (0)

  int cur = 0;
  STAGE(0, 0);
  __syncthreads();  // drains vmcnt(0): buf0 ready

  for (int kvi = 0; kvi <= qb; ++kvi) {
    const int kv0 = kvi * 64;
    if (kvi < qb) STAGE(cur ^ 1, kv0 + 64);  // prefetch next tile (in flight)

    const unsigned short* lkc = lk[cur];
    const unsigned short* lvc = lvt[cur];

    // S = Q K^T  (per wave: 16 q x 64 kv), already in log2 domain
    f32x4 s[4];
#pragma unroll
    for (int f = 0; f < 4; ++f) {
      const int row = 16 * f + c;
      const int sw = (row & 7) << 4;
      U8 k0, k1;
      k0.s = *(const u16x8*)((const char*)lkc + row * 128 + ((16 * g) ^ sw));
      k1.s = *(const u16x8*)((const char*)lkc + row * 128 + ((16 * g + 64) ^ sw));
      f32x4 z = {0.f, 0.f, 0.f, 0.f};
      z = MFMA16(qf0.b, k0.b, z);
      z = MFMA16(qf1.b, k1.b, z);
      s[f] = z;
    }
    // causal mask (only the diagonal tile needs it)
    if (kvi == qb) {
#pragma unroll
      for (int f = 0; f < 4; ++f) {
        const int kvcol = kv0 + 16 * f + c;
#pragma unroll
        for (int r = 0; r < 4; ++r) {
          const int qq = q0 + 16 * w + 4 * g + r;
          if (kvcol > qq) s[f][r] = -1e30f;
        }
      }
    }
    // online softmax (exp2 domain): rows in (g, r), cols across 16 lanes
    float alpha[4];
#pragma unroll
    for (int r = 0; r < 4; ++r) {
      float rm = fmaxf(fmaxf(s[0][r], s[1][r]), fmaxf(s[2][r], s[3][r]));
      rm = fmaxf(rm, __shfl_xor(rm, 1));
      rm = fmaxf(rm, __shfl_xor(rm, 2));
      rm = fmaxf(rm, __shfl_xor(rm, 4));
      rm = fmaxf(rm, __shfl_xor(rm, 8));
      const float mn = fmaxf(m[r], rm);
      float rs = 0.f;
#pragma unroll
      for (int f = 0; f < 4; ++f) {
        const float p = exp2f(s[f][r] - mn);
        s[f][r] = p;
        rs += p;
      }
      rs += __shfl_xor(rs, 1);
      rs += __shfl_xor(rs, 2);
      rs += __shfl_xor(rs, 4);
      rs += __shfl_xor(rs, 8);
      const float a = exp2f(m[r] - mn);
      alpha[r] = a;
      ls[r] = ls[r] * a + rs;
      m[r] = mn;
    }
#pragma unroll
    for (int df = 0; df < 4; ++df)
#pragma unroll
      for (int r = 0; r < 4; ++r) acc_o[df][r] *= alpha[r];

    // P -> per-wave LDS (re-layout for PV A-operand)
    unsigned short* lpw = &lp[w][0];
#pragma unroll
    for (int f = 0; f < 4; ++f)
#pragma unroll
      for (int r = 0; r < 4; ++r)
        lpw[(4 * g + r) * 72 + 16 * f + c] = f2bf(s[f][r]);

    // O += P V   (A = P [16q x 64kv], B = V^T rows d, k = kv contiguous)
#pragma unroll
    for (int half = 0; half < 2; ++half) {
      U8 pf;
      pf.s = *(const u16x8*)((const char*)lpw + c * 144 + 16 * g + 64 * half);
#pragma unroll
      for (int df = 0; df < 4; ++df) {
        const int row = 16 * df + c;
        const int sw = (row & 7) << 4;
        U8 vf;
        vf.s = *(const u16x8*)((const char*)lvc + row * 128 + ((16 * g + 64 * half) ^ sw));
        acc_o[df] = MFMA16(pf.b, vf.b, acc_o[df]);
      }
    }
    __syncthreads();  // drains vmcnt(0): prefetched buf ready; LDS reads done
    cur ^= 1;
  }
#undef STAGE

  // epilogue: y = O / l, write [t][h*64+d]
#pragma unroll
  for (int r = 0; r < 4; ++r) {
    const float inv = 1.0f / ls[r];
    const int qq = q0 + 16 * w + 4 * g + r;
#pragma unroll
    for (int df = 0; df < 4; ++df)
      Y[(size_t)qq * 1024 + h * 64 + 16 * df + c] = f2bf(acc_o[df][r] * inv);
  }
}

// --------------------------- launcher --------------------------------------
extern "C" void kernel_launch(void* const* d_in, const int* in_sizes, int n_in,
                              void* d_out, int out_size, void* d_ws, size_t ws_size,
                              hipStream_t stream) {
  const float* x   = (const float*)d_in[0];
  const float* ve  = (const float*)d_in[1];
  const float* qw  = (const float*)d_in[2];
  const float* lam = (const float*)d_in[3];
  const float* pw  = (const float*)d_in[4];
  float* out = (float*)d_out;

  unsigned short* ws = (unsigned short*)d_ws;
  unsigned short* x_bf  = ws;                                // 4096*1024
  unsigned short* wqkv  = x_bf + (size_t)4096 * 1024;        // 3072*1024
  unsigned short* wproj = wqkv + (size_t)3072 * 1024;        // 1024*1024
  unsigned short* qkv   = wproj + (size_t)1024 * 1024;       // 4096*3072
  unsigned short* Qr    = qkv + (size_t)4096 * 3072;         // 16*4096*64
  unsigned short* Kr    = Qr + (size_t)4096 * 1024;
  unsigned short* Vm    = Kr + (size_t)4096 * 1024;
  unsigned short* VTt   = Vm + (size_t)4096 * 1024;
  unsigned short* Yb    = VTt + (size_t)4096 * 1024;
  float* ct = (float*)(Yb + (size_t)4096 * 1024);            // 4096*32
  float* st = ct + 4096 * 32;

  rope_tab<<<512, 256, 0, stream>>>(ct, st);
  cast_f2b8<<<2048, 256, 0, stream>>>(x, x_bf, 524288);
  cast_f2b8<<<1536, 256, 0, stream>>>(qw, wqkv, 393216);
  cast_f2b8<<<512, 256, 0, stream>>>(pw, wproj, 131072);
  gemm_bt<1><<<768, 256, 0, stream>>>(x_bf, wqkv, (void*)qkv, 4096, 3072, 1024);
  fuse_qkv<<<256, 256, 0, stream>>>(qkv, ve, lam, ct, st, Qr, Kr, Vm);
  transpose_v<<<1024, 256, 0, stream>>>(Vm, VTt);
  attn_fa<<<1024, 256, 0, stream>>>(Qr, Kr, VTt, Yb);
  gemm_bt<0><<<256, 256, 0, stream>>>(Yb, wproj, (void*)out, 4096, 1024, 1024);
}